// Round 21
// baseline (229.087 us; speedup 1.0000x reference)
//
#include <hip/hip_runtime.h>
#include <hip/hip_bf16.h>

#define N_NODES 50000
#define N_EDGES 600000
#define F_IN    92
#define KPAD    96
#define HID     32
#define HEADS   8
#define D1      256
#define HS_LD   264   // D1 + 8: conflict-free LDS staging stride
#define G_GRAPHS 512
#define EPSV    1e-5f
#define NCHUNK  49   // ceil(50000/1024)
#define DEGBLK  2344 // ceil(600000/256)

using short8  = __attribute__((ext_vector_type(8))) short;
using f32x4   = __attribute__((ext_vector_type(4))) float;
using f32x2   = __attribute__((ext_vector_type(2))) float;

__device__ __forceinline__ float bf2f(unsigned short u) {
    return __uint_as_float(((unsigned)u) << 16);
}
__device__ __forceinline__ unsigned short f2bf(float f) {
    unsigned u = __float_as_uint(f);
    return (unsigned short)((u + 0x7FFFu + ((u >> 16) & 1u)) >> 16);  // RNE
}

// zero deg: 50000 ints = 12500 int4, 49 blocks x 256 threads
__global__ void k_zero(int* __restrict__ deg) {
    int i = blockIdx.x * 256 + threadIdx.x;
    if (i < N_NODES / 4) {
        int4 z = {0, 0, 0, 0};
        *(int4*)(deg + i * 4) = z;
    }
}

// ---------------- CSR build + setup (merged grid) ----------------

__global__ __launch_bounds__(256) void k_deg_setup(
        const int* __restrict__ ei, int* __restrict__ deg,
        const float* __restrict__ W1, const float* __restrict__ W2,
        const float* __restrict__ We1, const float* __restrict__ ae1,
        const float* __restrict__ We2, const float* __restrict__ ae2,
        const float* __restrict__ as1, const float* __restrict__ ad1,
        const float* __restrict__ b1, const float* __restrict__ g1,
        const float* __restrict__ be1, const float* __restrict__ m1,
        const float* __restrict__ v1,
        const float* __restrict__ b2, const float* __restrict__ g2,
        const float* __restrict__ be2, const float* __restrict__ m2,
        const float* __restrict__ v2,
        unsigned short* __restrict__ W1p, unsigned short* __restrict__ W2p,
        float* __restrict__ va, float* __restrict__ wedot,
        float* __restrict__ bnA1, float* __restrict__ bnB1,
        float* __restrict__ bnA2, float* __restrict__ bnB2) {
    int blk = blockIdx.x, t = threadIdx.x;
    if (blk < DEGBLK) {                 // degree histogram
        int e = blk * 256 + t;
        if (e < N_EDGES) atomicAdd(&deg[ei[N_EDGES + e]], 1);
        return;
    }
    int b = blk - DEGBLK;               // 0..135: setup work
    if (b < 96) {                       // pack W1 (zero-pad K to 96)
        int gid = b * 256 + t;          // covers KPAD*D1 = 24576
        int k = gid >> 8, col = gid & 255;
        unsigned short v = 0;
        if (k < F_IN) v = f2bf(W1[k * D1 + col]);
        W1p[(((k >> 3) * D1) + col) * 8 + (k & 7)] = v;
    } else if (b < 128) {               // pack W2
        int gid = (b - 96) * 256 + t;   // covers 8192
        int k = gid >> 5, col = gid & 31;
        W2p[(((k >> 3) * 32) + col) * 8 + (k & 7)] = f2bf(W2[gid]);
    } else if (b < 134) {               // va
        int gid = (b - 128) * 256 + t;
        if (gid < 2 * HEADS * F_IN) {
            int which = gid / (HEADS * F_IN), rem = gid % (HEADS * F_IN);
            int h = rem / F_IN, k = rem % F_IN;
            const float* av = which ? ad1 : as1;
            float s = 0.f;
            #pragma unroll 8
            for (int c = 0; c < HID; ++c) s += W1[k * D1 + h * HID + c] * av[h * HID + c];
            va[gid] = s;
        }
    } else if (b == 134) {              // wedot
        if (t < HEADS) {
            float a = 0.f;
            for (int c = 0; c < HID; ++c) a += We1[t * HID + c] * ae1[t * HID + c];
            wedot[t] = a;
        } else if (t == HEADS) {
            float a = 0.f;
            for (int c = 0; c < HID; ++c) a += We2[c] * ae2[c];
            wedot[HEADS] = a;
        }
    } else {                            // BN fold: y = acc*inv*A + B  (pre-relu)
        if (t < D1) {
            float sc = g1[t] * __frsqrt_rn(v1[t] + EPSV);
            bnA1[t] = sc;
            bnB1[t] = (b1[t] - m1[t]) * sc + be1[t];
        }
        if (t < HID) {
            float sc = g2[t] * __frsqrt_rn(v2[t] + EPSV);
            bnA2[t] = sc;
            bnB2[t] = (b2[t] - m2[t]) * sc + be2[t];
        }
    }
}

// fused scan: each block computes its own global prefix (redundant sum of
// preceding chunks) then scans its 1024-node chunk. One dispatch.
__global__ __launch_bounds__(256) void k_scan1(const int* __restrict__ deg,
                                               int* __restrict__ row_off,
                                               int* __restrict__ cursor) {
    int b = blockIdx.x;
    int t = threadIdx.x;
    __shared__ int sm[256];
    __shared__ int smp;
    // global prefix: sum deg[0 .. b*1024)
    int p = 0;
    for (int i = t; i < b * 1024; i += 256) p += deg[i];
    sm[t] = p;
    __syncthreads();
    if (t < 64) {
        int v = sm[t] + sm[t + 64] + sm[t + 128] + sm[t + 192];
        #pragma unroll
        for (int off = 32; off; off >>= 1) v += __shfl_down(v, off, 64);
        if (t == 0) smp = v;
    }
    __syncthreads();
    // local chunk scan
    int base_i = b * 1024 + t * 4;
    int v4[4]; int s = 0;
    #pragma unroll
    for (int j = 0; j < 4; ++j) {
        int i = base_i + j;
        v4[j] = (i < N_NODES) ? deg[i] : 0;
        s += v4[j];
    }
    sm[t] = s;
    __syncthreads();
    int val = s;
    for (int off = 1; off < 256; off <<= 1) {
        int add = (t >= off) ? sm[t - off] : 0;
        __syncthreads();
        val += add;
        sm[t] = val;
        __syncthreads();
    }
    int base = smp + (val - s);   // exclusive prefix
    #pragma unroll
    for (int j = 0; j < 4; ++j) {
        int i = base_i + j;
        if (i < N_NODES) { row_off[i] = base; cursor[i] = base; }
        base += v4[j];
    }
}

__global__ void k_fill(const int* __restrict__ ei, const float* __restrict__ ea,
                       int* __restrict__ cursor, int2* __restrict__ adj) {
    int e = blockIdx.x * 256 + threadIdx.x;
    if (e < N_EDGES) {
        int d = ei[N_EDGES + e];
        int pos = atomicAdd(&cursor[d], 1);
        adj[pos] = make_int2(ei[e], __float_as_int(ea[e]));
    }
}

// ---------------- conv1: x -> h1f8 (fp8, node-major) + alpha logits ----------------
__global__ __launch_bounds__(256) void k_conv1(const float* __restrict__ x,
                                               const unsigned short* __restrict__ W1p,
                                               const float* __restrict__ va,
                                               unsigned char* __restrict__ h1f8,
                                               float* __restrict__ al_s,
                                               float* __restrict__ al_d) {
    __shared__ float xs[16 * F_IN];
    __shared__ unsigned short xbs[16 * KPAD];
    __shared__ float hs[16 * HS_LD];
    int n0 = blockIdx.x * 16;
    int t = threadIdx.x;
    for (int i = t; i < 16 * F_IN; i += 256)
        xs[i] = x[(size_t)n0 * F_IN + i];
    __syncthreads();
    // bf16 copy (padded) for MFMA fragments
    for (int i = t; i < 16 * KPAD; i += 256) {
        int r = i / KPAD, k = i - r * KPAD;
        xbs[i] = (k < F_IN) ? f2bf(xs[r * F_IN + k]) : (unsigned short)0;
    }
    // exact f32 attention logits: thread t -> (row t>>4, vec t&15)
    {
        int r = t >> 4, j = t & 15;
        const float* vp = va + j * F_IN;
        const float* xr = xs + r * F_IN;
        float s = 0.f;
        for (int k = 0; k < F_IN; ++k) s += xr[k] * vp[k];
        if (j < 8) al_s[(n0 + r) * HEADS + j] = s;
        else       al_d[(n0 + r) * HEADS + (j - 8)] = s;
    }
    __syncthreads();
    // MFMA: wave wid covers cols wid*64..wid*64+63
    int wid = t >> 6, l = t & 63;
    int g = l >> 4, c16 = l & 15;
    const short8* xb = (const short8*)(xbs + c16 * KPAD + g * 8);
    short8 af0 = xb[0], af1 = xb[4], af2 = xb[8];   // k = g*8 + {0,32,64}
    const short8* wp = (const short8*)W1p;
    #pragma unroll
    for (int ct = 0; ct < 4; ++ct) {
        int col = (wid * 4 + ct) * 16 + c16;
        f32x4 acc = {0.f, 0.f, 0.f, 0.f};
        acc = __builtin_amdgcn_mfma_f32_16x16x32_bf16(af0, wp[(0 * 4 + g) * D1 + col], acc, 0, 0, 0);
        acc = __builtin_amdgcn_mfma_f32_16x16x32_bf16(af1, wp[(1 * 4 + g) * D1 + col], acc, 0, 0, 0);
        acc = __builtin_amdgcn_mfma_f32_16x16x32_bf16(af2, wp[(2 * 4 + g) * D1 + col], acc, 0, 0, 0);
        #pragma unroll
        for (int r = 0; r < 4; ++r)
            hs[(g * 4 + r) * HS_LD + col] = acc[r];
    }
    __syncthreads();
    // pack fp8: thread t -> row t>>4, quad q=t&15; 4 iters of 16B-read/4B-store
    {
        int r = t >> 4, q = t & 15;
        #pragma unroll
        for (int j = 0; j < 4; ++j) {
            const float* src = hs + r * HS_LD + q * 4 + j * 64;
            int lo = __builtin_amdgcn_cvt_pk_fp8_f32(src[0], src[1], 0, false);
            int pk = __builtin_amdgcn_cvt_pk_fp8_f32(src[2], src[3], lo, true);
            *(int*)(h1f8 + (size_t)(n0 + r) * D1 + q * 4 + j * 64) = pk;
        }
    }
}

// ---------------- aggregation conv1 (wave/node, fp8 gather, 8x edge unroll) ----------------
__global__ __launch_bounds__(256) void k_aggr1(
        const int* __restrict__ row_off, const int* __restrict__ deg,
        const int2* __restrict__ adj,
        const unsigned char* __restrict__ h1f8,
        const float* __restrict__ al_s, const float* __restrict__ al_d,
        const float* __restrict__ wedot,
        const float* __restrict__ bnA1, const float* __restrict__ bnB1,
        unsigned short* __restrict__ h1p) {
    int wid = threadIdx.x >> 6, l = threadIdx.x & 63;
    int n = blockIdx.x * 4 + wid;
    if (n >= N_NODES) return;
    int h = l >> 3;
    float wd = wedot[h];
    float dn = al_d[n * HEADS + h];
    int r0 = row_off[n], cnt = deg[n];
    float a0 = 0.f, a1 = 0.f, a2 = 0.f, a3 = 0.f, den = 0.f, ea_sum = 0.f;
    for (int base = 0; base < cnt; base += 64) {
        int m = cnt - base; if (m > 64) m = 64;
        int sl = 0; float el = 0.f;
        if (l < m) {
            int2 se = adj[r0 + base + l];
            sl = se.x;
            el = __int_as_float(se.y);
        }
        int i = 0;
        for (; i + 7 < m; i += 8) {
            int sv[8]; float ev[8], asv[8]; unsigned wv[8];
            #pragma unroll
            for (int j = 0; j < 8; ++j) {
                sv[j] = __shfl(sl, i + j, 64);
                ev[j] = __shfl(el, i + j, 64);
            }
            #pragma unroll
            for (int j = 0; j < 8; ++j) asv[j] = al_s[sv[j] * HEADS + h];
            #pragma unroll
            for (int j = 0; j < 8; ++j)
                wv[j] = *(const unsigned*)(h1f8 + (size_t)sv[j] * D1 + l * 4);
            #pragma unroll
            for (int j = 0; j < 8; ++j) {
                float aa = asv[j] + dn + ev[j] * wd;
                aa = aa > 0.f ? aa : 0.2f * aa;
                float w = __expf(aa);
                den += w;
                ea_sum += ev[j];
                f32x2 lo = __builtin_amdgcn_cvt_pk_f32_fp8(wv[j], false);
                f32x2 hi = __builtin_amdgcn_cvt_pk_f32_fp8(wv[j], true);
                a0 += w * lo.x; a1 += w * lo.y;
                a2 += w * hi.x; a3 += w * hi.y;
            }
        }
        for (; i < m; ++i) {   // tail (<=7)
            int s = __shfl(sl, i, 64);
            float eav = __shfl(el, i, 64);
            float a = al_s[s * HEADS + h] + dn + eav * wd;
            a = a > 0.f ? a : 0.2f * a;
            float w = __expf(a);
            den += w;
            ea_sum += eav;
            unsigned w8 = *(const unsigned*)(h1f8 + (size_t)s * D1 + l * 4);
            f32x2 lo = __builtin_amdgcn_cvt_pk_f32_fp8(w8, false);
            f32x2 hi = __builtin_amdgcn_cvt_pk_f32_fp8(w8, true);
            a0 += w * lo.x; a1 += w * lo.y;
            a2 += w * hi.x; a3 += w * hi.y;
        }
    }
    {   // self loop, attr = mean of incoming (0 if none)
        float la = ea_sum / (float)(cnt > 0 ? cnt : 1);
        float a = al_s[n * HEADS + h] + dn + la * wd;
        a = a > 0.f ? a : 0.2f * a;
        float w = __expf(a);
        den += w;
        unsigned w8 = *(const unsigned*)(h1f8 + (size_t)n * D1 + l * 4);
        f32x2 lo = __builtin_amdgcn_cvt_pk_f32_fp8(w8, false);
        f32x2 hi = __builtin_amdgcn_cvt_pk_f32_fp8(w8, true);
        a0 += w * lo.x; a1 += w * lo.y;
        a2 += w * hi.x; a3 += w * hi.y;
    }
    float inv = 1.f / den;
    int c = l * 4;
    float4 A = *(const float4*)(bnA1 + c);
    float4 B = *(const float4*)(bnB1 + c);
    ushort4 o;
    o.x = f2bf(fmaxf(a0 * inv * A.x + B.x, 0.f));
    o.y = f2bf(fmaxf(a1 * inv * A.y + B.y, 0.f));
    o.z = f2bf(fmaxf(a2 * inv * A.z + B.z, 0.f));
    o.w = f2bf(fmaxf(a3 * inv * A.w + B.w, 0.f));
    *(ushort4*)(h1p + (size_t)n * D1 + c) = o;
}

// ---------------- conv2 ----------------

// h1p(bf16) @ W2p(bf16) -> h2f8 (fp8 e4m3) via MFMA, fused alpha2 (f32-exact).
__global__ __launch_bounds__(256) void k_gemm2(const unsigned short* __restrict__ h1p,
                                               const unsigned short* __restrict__ W2p,
                                               const float* __restrict__ as2,
                                               const float* __restrict__ ad2,
                                               unsigned char* __restrict__ h2f8,
                                               float* __restrict__ al_s2,
                                               float* __restrict__ al_d2) {
    int wid = threadIdx.x >> 6, l = threadIdx.x & 63;
    int wave = blockIdx.x * 4 + wid;
    if (wave >= N_NODES / 16) return;
    int n0 = wave * 16;
    int g = l >> 4;        // k-subgroup 0..3
    int c16 = l & 15;      // col within 16 / A-row within 16
    f32x4 acc0 = {0.f, 0.f, 0.f, 0.f};
    f32x4 acc1 = {0.f, 0.f, 0.f, 0.f};
    const short8* ap = (const short8*)(h1p + (size_t)(n0 + c16) * D1 + g * 8);
    const short8* wp = (const short8*)W2p;
    #pragma unroll
    for (int ks = 0; ks < 8; ++ks) {
        short8 afrag = ap[ks * 4];                     // +ks*32 bf16
        short8 b0 = wp[(ks * 4 + g) * 32 + c16];
        short8 b1 = wp[(ks * 4 + g) * 32 + 16 + c16];
        acc0 = __builtin_amdgcn_mfma_f32_16x16x32_bf16(afrag, b0, acc0, 0, 0, 0);
        acc1 = __builtin_amdgcn_mfma_f32_16x16x32_bf16(afrag, b1, acc1, 0, 0, 0);
    }
    // C layout: col = lane&15, row = (lane>>4)*4 + reg
    float s0 = as2[c16], s1 = as2[16 + c16];
    float d0 = ad2[c16], d1 = ad2[16 + c16];
    float ps[4], pd[4];
    #pragma unroll
    for (int r = 0; r < 4; ++r) {
        int node = n0 + g * 4 + r;
        int p0 = __builtin_amdgcn_cvt_pk_fp8_f32(acc0[r], acc0[r], 0, false);
        int p1 = __builtin_amdgcn_cvt_pk_fp8_f32(acc1[r], acc1[r], 0, false);
        h2f8[(size_t)node * HID + c16]      = (unsigned char)p0;
        h2f8[(size_t)node * HID + 16 + c16] = (unsigned char)p1;
        ps[r] = acc0[r] * s0 + acc1[r] * s1;
        pd[r] = acc0[r] * d0 + acc1[r] * d1;
    }
    #pragma unroll
    for (int off = 1; off < 16; off <<= 1) {
        #pragma unroll
        for (int r = 0; r < 4; ++r) {
            ps[r] += __shfl_xor(ps[r], off, 64);
            pd[r] += __shfl_xor(pd[r], off, 64);
        }
    }
    if (c16 == 0) {
        #pragma unroll
        for (int r = 0; r < 4; ++r) {
            int node = n0 + g * 4 + r;
            al_s2[node] = ps[r];
            al_d2[node] = pd[r];
        }
    }
}

// aggregation conv2: oct-split — 8-lane group per edge, 8 edges/iter,
// lane owns 4 channels (uint fp8 gather). Cross-group reduce at end.
__global__ __launch_bounds__(256) void k_aggr2(
        const int* __restrict__ row_off, const int* __restrict__ deg,
        const int2* __restrict__ adj,
        const unsigned char* __restrict__ h2f8,
        const float* __restrict__ al_s2, const float* __restrict__ al_d2,
        const float* __restrict__ wedot,
        const float* __restrict__ bnA2, const float* __restrict__ bnB2,
        float* __restrict__ h2p) {
    int wid = threadIdx.x >> 6, l = threadIdx.x & 63;
    int n = blockIdx.x * 4 + wid;
    if (n >= N_NODES) return;
    int g = l >> 3, c8 = l & 7;           // edge-group, channel-quad index
    float wd = wedot[HEADS];
    float dn = al_d2[n];
    int r0 = row_off[n], cnt = deg[n];
    float a0 = 0.f, a1 = 0.f, a2 = 0.f, a3 = 0.f, den = 0.f, ea_sum = 0.f;
    for (int base = 0; base < cnt; base += 64) {
        int m = cnt - base; if (m > 64) m = 64;
        int sl = 0; float el = 0.f;
        if (l < m) {
            int2 se = adj[r0 + base + l];
            sl = se.x;
            el = __int_as_float(se.y);
        }
        for (int i = 0; i < m; i += 8) {
            int j = i + g;
            int jj = j < m ? j : 0;
            int s = __shfl(sl, jj, 64);
            float eav = __shfl(el, jj, 64);
            if (j < m) {
                float a = al_s2[s] + dn + eav * wd;
                a = a > 0.f ? a : 0.2f * a;
                float w = __expf(a);
                den += w;
                ea_sum += eav;
                unsigned w8 = *(const unsigned*)(h2f8 + (size_t)s * HID + c8 * 4);
                f32x2 lo = __builtin_amdgcn_cvt_pk_f32_fp8(w8, false);
                f32x2 hi = __builtin_amdgcn_cvt_pk_f32_fp8(w8, true);
                a0 += w * lo.x; a1 += w * lo.y;
                a2 += w * hi.x; a3 += w * hi.y;
            }
        }
    }
    // reduce across the 8 edge-groups (c8 stays aligned under xor of bits 3..5)
    #pragma unroll
    for (int off = 8; off < 64; off <<= 1) {
        a0 += __shfl_xor(a0, off, 64);
        a1 += __shfl_xor(a1, off, 64);
        a2 += __shfl_xor(a2, off, 64);
        a3 += __shfl_xor(a3, off, 64);
        den += __shfl_xor(den, off, 64);
        ea_sum += __shfl_xor(ea_sum, off, 64);
    }
    {   // self loop (all lanes add identically post-reduce)
        float la = ea_sum / (float)(cnt > 0 ? cnt : 1);
        float a = al_s2[n] + dn + la * wd;
        a = a > 0.f ? a : 0.2f * a;
        float w = __expf(a);
        den += w;
        unsigned w8 = *(const unsigned*)(h2f8 + (size_t)n * HID + c8 * 4);
        f32x2 lo = __builtin_amdgcn_cvt_pk_f32_fp8(w8, false);
        f32x2 hi = __builtin_amdgcn_cvt_pk_f32_fp8(w8, true);
        a0 += w * lo.x; a1 += w * lo.y;
        a2 += w * hi.x; a3 += w * hi.y;
    }
    if (g == 0) {
        float inv = 1.f / den;
        int c = c8 * 4;
        float4 A = *(const float4*)(bnA2 + c);
        float4 B = *(const float4*)(bnB2 + c);
        float4 y;
        y.x = fmaxf(a0 * inv * A.x + B.x, 0.f);
        y.y = fmaxf(a1 * inv * A.y + B.y, 0.f);
        y.z = fmaxf(a2 * inv * A.z + B.z, 0.f);
        y.w = fmaxf(a3 * inv * A.w + B.w, 0.f);
        *(float4*)(h2p + (size_t)n * HID + c) = y;
    }
}

// pool (mean over sorted batch segments) + fc, one block per graph
__global__ __launch_bounds__(64) void k_poolfc(const float* __restrict__ h2p,
                                               const int* __restrict__ batch,
                                               const float* __restrict__ fcW,
                                               const float* __restrict__ fcb,
                                               float* __restrict__ out) {
    int g = blockIdx.x;
    int l = threadIdx.x;
    auto lb = [&](int key) {
        int lo = 0, hi = N_NODES;
        while (lo < hi) {
            int mid = (lo + hi) >> 1;
            if (batch[mid] < key) lo = mid + 1; else hi = mid;
        }
        return lo;
    };
    int s0 = lb(g), s1 = lb(g + 1);
    int c = l & 31, half = l >> 5;
    float acc = 0.f;
    for (int r = s0 + half; r < s1; r += 2)
        acc += h2p[(size_t)r * HID + c];
    acc += __shfl_xor(acc, 32, 64);
    int cn = s1 - s0;
    float mean = acc / (float)(cn > 0 ? cn : 1);
    float p = mean * fcW[c];
    #pragma unroll
    for (int off = 1; off < 32; off <<= 1) p += __shfl_xor(p, off, 64);
    if (l == 0) out[g] = p + fcb[0];
}

// ---------------- launch ----------------

extern "C" void kernel_launch(void* const* d_in, const int* in_sizes, int n_in,
                              void* d_out, int out_size, void* d_ws, size_t ws_size,
                              hipStream_t stream) {
    const float* x    = (const float*)d_in[0];
    const int*   ei   = (const int*)  d_in[1];
    const float* ea   = (const float*)d_in[2];
    const int*   batch= (const int*)  d_in[3];
    const float* W1   = (const float*)d_in[4];
    const float* We1  = (const float*)d_in[5];
    const float* as1  = (const float*)d_in[6];
    const float* ad1  = (const float*)d_in[7];
    const float* ae1  = (const float*)d_in[8];
    const float* b1   = (const float*)d_in[9];
    const float* g1   = (const float*)d_in[10];
    const float* be1  = (const float*)d_in[11];
    const float* m1   = (const float*)d_in[12];
    const float* v1   = (const float*)d_in[13];
    const float* W2   = (const float*)d_in[14];
    const float* We2  = (const float*)d_in[15];
    const float* as2  = (const float*)d_in[16];
    const float* ad2  = (const float*)d_in[17];
    const float* ae2  = (const float*)d_in[18];
    const float* b2   = (const float*)d_in[19];
    const float* g2   = (const float*)d_in[20];
    const float* be2  = (const float*)d_in[21];
    const float* m2   = (const float*)d_in[22];
    const float* v2   = (const float*)d_in[23];
    const float* fcW  = (const float*)d_in[24];
    const float* fcb  = (const float*)d_in[25];
    float* out = (float*)d_out;

    char* ws = (char*)d_ws;
    size_t off = 0;
    auto alloc = [&](size_t bytes) -> void* {
        void* p = ws + off;
        off += (bytes + 255) & ~(size_t)255;
        return p;
    };
    int*   deg     = (int*)  alloc((size_t)N_NODES * 4);
    int*   row_off = (int*)  alloc((size_t)N_NODES * 4);
    int*   cursor  = (int*)  alloc((size_t)N_NODES * 4);
    int2*  adj     = (int2*) alloc((size_t)N_EDGES * 8);
    float* al_s1   = (float*)alloc((size_t)N_NODES * HEADS * 4);
    float* al_d1   = (float*)alloc((size_t)N_NODES * HEADS * 4);
    float* al_s2   = (float*)alloc((size_t)N_NODES * 4);
    float* al_d2   = (float*)alloc((size_t)N_NODES * 4);
    float* wedot   = (float*)alloc(16 * 4);
    float* va      = (float*)alloc((size_t)2 * HEADS * F_IN * 4);
    float* bnA1    = (float*)alloc((size_t)D1 * 4);
    float* bnB1    = (float*)alloc((size_t)D1 * 4);
    float* bnA2    = (float*)alloc((size_t)HID * 4);
    float* bnB2    = (float*)alloc((size_t)HID * 4);
    unsigned short* W1p = (unsigned short*)alloc((size_t)KPAD * D1 * 2);
    unsigned short* W2p = (unsigned short*)alloc((size_t)D1 * HID * 2);
    unsigned char*  h1f8 = (unsigned char*)alloc((size_t)N_NODES * D1);
    unsigned short* h1p = (unsigned short*)alloc((size_t)N_NODES * D1 * 2);
    unsigned char*  h2f8 = (unsigned char*)alloc((size_t)N_NODES * HID);
    float* h2p     = (float*)alloc((size_t)N_NODES * HID * 4);
    (void)ws_size; (void)in_sizes; (void)n_in; (void)out_size;

    k_zero<<<(N_NODES / 4 + 255) / 256, 256, 0, stream>>>(deg);
    k_deg_setup<<<DEGBLK + 136, 256, 0, stream>>>(ei, deg, W1, W2, We1, ae1, We2, ae2,
                                                  as1, ad1, b1, g1, be1, m1, v1,
                                                  b2, g2, be2, m2, v2,
                                                  W1p, W2p, va, wedot,
                                                  bnA1, bnB1, bnA2, bnB2);
    k_scan1<<<NCHUNK, 256, 0, stream>>>(deg, row_off, cursor);
    k_fill<<<(N_EDGES + 255) / 256, 256, 0, stream>>>(ei, ea, cursor, adj);

    k_conv1<<<N_NODES / 16, 256, 0, stream>>>(x, W1p, va, h1f8, al_s1, al_d1);
    k_aggr1<<<(N_NODES + 3) / 4, 256, 0, stream>>>(row_off, deg, adj,
                                                   h1f8, al_s1, al_d1, wedot,
                                                   bnA1, bnB1, h1p);

    k_gemm2<<<(N_NODES / 16 + 3) / 4, 256, 0, stream>>>(h1p, W2p, as2, ad2, h2f8, al_s2, al_d2);
    k_aggr2<<<(N_NODES + 3) / 4, 256, 0, stream>>>(row_off, deg, adj,
                                                   h2f8, al_s2, al_d2, wedot, bnA2, bnB2, h2p);
    k_poolfc<<<G_GRAPHS, 64, 0, stream>>>(h2p, batch, fcW, fcb, out);
}

// Round 22
// 200.992 us; speedup vs baseline: 1.1398x; 1.1398x over previous
//
#include <hip/hip_runtime.h>
#include <hip/hip_bf16.h>

#define N_NODES 50000
#define N_EDGES 600000
#define F_IN    92
#define KPAD    96
#define HID     32
#define HEADS   8
#define D1      256
#define HS_LD   264   // D1 + 8: conflict-free LDS staging stride
#define G_GRAPHS 512
#define EPSV    1e-5f
#define NCHUNK  49   // ceil(50000/1024)
#define DEGBLK  2344 // ceil(600000/256)

using short8  = __attribute__((ext_vector_type(8))) short;
using f32x4   = __attribute__((ext_vector_type(4))) float;
using f32x2   = __attribute__((ext_vector_type(2))) float;

__device__ __forceinline__ float bf2f(unsigned short u) {
    return __uint_as_float(((unsigned)u) << 16);
}
__device__ __forceinline__ unsigned short f2bf(float f) {
    unsigned u = __float_as_uint(f);
    return (unsigned short)((u + 0x7FFFu + ((u >> 16) & 1u)) >> 16);  // RNE
}

// ---------------- CSR build + setup (merged grid) ----------------

__global__ __launch_bounds__(256) void k_deg_setup(
        const int* __restrict__ ei, int* __restrict__ deg,
        const float* __restrict__ W1, const float* __restrict__ W2,
        const float* __restrict__ We1, const float* __restrict__ ae1,
        const float* __restrict__ We2, const float* __restrict__ ae2,
        const float* __restrict__ as1, const float* __restrict__ ad1,
        const float* __restrict__ b1, const float* __restrict__ g1,
        const float* __restrict__ be1, const float* __restrict__ m1,
        const float* __restrict__ v1,
        const float* __restrict__ b2, const float* __restrict__ g2,
        const float* __restrict__ be2, const float* __restrict__ m2,
        const float* __restrict__ v2,
        unsigned short* __restrict__ W1p, unsigned short* __restrict__ W2p,
        float* __restrict__ va, float* __restrict__ wedot,
        float* __restrict__ bnA1, float* __restrict__ bnB1,
        float* __restrict__ bnA2, float* __restrict__ bnB2) {
    int blk = blockIdx.x, t = threadIdx.x;
    if (blk < DEGBLK) {                 // degree histogram
        int e = blk * 256 + t;
        if (e < N_EDGES) atomicAdd(&deg[ei[N_EDGES + e]], 1);
        return;
    }
    int b = blk - DEGBLK;               // 0..135: setup work
    if (b < 96) {                       // pack W1 (zero-pad K to 96)
        int gid = b * 256 + t;          // covers KPAD*D1 = 24576
        int k = gid >> 8, col = gid & 255;
        unsigned short v = 0;
        if (k < F_IN) v = f2bf(W1[k * D1 + col]);
        W1p[(((k >> 3) * D1) + col) * 8 + (k & 7)] = v;
    } else if (b < 128) {               // pack W2
        int gid = (b - 96) * 256 + t;   // covers 8192
        int k = gid >> 5, col = gid & 31;
        W2p[(((k >> 3) * 32) + col) * 8 + (k & 7)] = f2bf(W2[gid]);
    } else if (b < 134) {               // va
        int gid = (b - 128) * 256 + t;
        if (gid < 2 * HEADS * F_IN) {
            int which = gid / (HEADS * F_IN), rem = gid % (HEADS * F_IN);
            int h = rem / F_IN, k = rem % F_IN;
            const float* av = which ? ad1 : as1;
            float s = 0.f;
            #pragma unroll 8
            for (int c = 0; c < HID; ++c) s += W1[k * D1 + h * HID + c] * av[h * HID + c];
            va[gid] = s;
        }
    } else if (b == 134) {              // wedot
        if (t < HEADS) {
            float a = 0.f;
            for (int c = 0; c < HID; ++c) a += We1[t * HID + c] * ae1[t * HID + c];
            wedot[t] = a;
        } else if (t == HEADS) {
            float a = 0.f;
            for (int c = 0; c < HID; ++c) a += We2[c] * ae2[c];
            wedot[HEADS] = a;
        }
    } else {                            // BN fold: y = acc*inv*A + B  (pre-relu)
        if (t < D1) {
            float sc = g1[t] * __frsqrt_rn(v1[t] + EPSV);
            bnA1[t] = sc;
            bnB1[t] = (b1[t] - m1[t]) * sc + be1[t];
        }
        if (t < HID) {
            float sc = g2[t] * __frsqrt_rn(v2[t] + EPSV);
            bnA2[t] = sc;
            bnB2[t] = (b2[t] - m2[t]) * sc + be2[t];
        }
    }
}

__global__ void k_partial(const int* __restrict__ deg, int* __restrict__ partials) {
    int b = blockIdx.x;
    int s = 0;
    for (int j = 0; j < 4; ++j) {
        int i = b * 1024 + j * 256 + threadIdx.x;
        if (i < N_NODES) s += deg[i];
    }
    for (int off = 32; off; off >>= 1) s += __shfl_down(s, off, 64);
    __shared__ int sm[4];
    if ((threadIdx.x & 63) == 0) sm[threadIdx.x >> 6] = s;
    __syncthreads();
    if (threadIdx.x == 0) partials[b] = sm[0] + sm[1] + sm[2] + sm[3];
}

// per-chunk scan; each block derives its own prefix of partials (49 <= 64)
__global__ void k_scanc(const int* __restrict__ deg, const int* __restrict__ partials,
                        int* __restrict__ row_off, int* __restrict__ cursor) {
    int b = blockIdx.x;
    int t = threadIdx.x;
    __shared__ int smp;
    if (t < 64) {
        int pv = (t < b) ? partials[t] : 0;
        #pragma unroll
        for (int off = 32; off; off >>= 1) pv += __shfl_down(pv, off, 64);
        if (t == 0) smp = pv;
    }
    int base_i = b * 1024 + t * 4;
    int v[4]; int s = 0;
    #pragma unroll
    for (int j = 0; j < 4; ++j) {
        int i = base_i + j;
        v[j] = (i < N_NODES) ? deg[i] : 0;
        s += v[j];
    }
    __shared__ int sm[256];
    sm[t] = s;
    __syncthreads();
    int val = s;
    for (int off = 1; off < 256; off <<= 1) {
        int add = (t >= off) ? sm[t - off] : 0;
        __syncthreads();
        val += add;
        sm[t] = val;
        __syncthreads();
    }
    int base = smp + (val - s);   // exclusive prefix
    #pragma unroll
    for (int j = 0; j < 4; ++j) {
        int i = base_i + j;
        if (i < N_NODES) { row_off[i] = base; cursor[i] = base; }
        base += v[j];
    }
}

__global__ void k_fill(const int* __restrict__ ei, const float* __restrict__ ea,
                       int* __restrict__ cursor, int2* __restrict__ adj) {
    int e = blockIdx.x * 256 + threadIdx.x;
    if (e < N_EDGES) {
        int d = ei[N_EDGES + e];
        int pos = atomicAdd(&cursor[d], 1);
        adj[pos] = make_int2(ei[e], __float_as_int(ea[e]));
    }
}

// ---------------- conv1: x -> h1f8 (fp8, node-major) + alpha logits ----------------
__global__ __launch_bounds__(256) void k_conv1(const float* __restrict__ x,
                                               const unsigned short* __restrict__ W1p,
                                               const float* __restrict__ va,
                                               unsigned char* __restrict__ h1f8,
                                               float* __restrict__ al_s,
                                               float* __restrict__ al_d) {
    __shared__ float xs[16 * F_IN];
    __shared__ unsigned short xbs[16 * KPAD];
    __shared__ float hs[16 * HS_LD];
    int n0 = blockIdx.x * 16;
    int t = threadIdx.x;
    for (int i = t; i < 16 * F_IN; i += 256)
        xs[i] = x[(size_t)n0 * F_IN + i];
    __syncthreads();
    // bf16 copy (padded) for MFMA fragments
    for (int i = t; i < 16 * KPAD; i += 256) {
        int r = i / KPAD, k = i - r * KPAD;
        xbs[i] = (k < F_IN) ? f2bf(xs[r * F_IN + k]) : (unsigned short)0;
    }
    // exact f32 attention logits: thread t -> (row t>>4, vec t&15)
    {
        int r = t >> 4, j = t & 15;
        const float* vp = va + j * F_IN;
        const float* xr = xs + r * F_IN;
        float s = 0.f;
        for (int k = 0; k < F_IN; ++k) s += xr[k] * vp[k];
        if (j < 8) al_s[(n0 + r) * HEADS + j] = s;
        else       al_d[(n0 + r) * HEADS + (j - 8)] = s;
    }
    __syncthreads();
    // MFMA: wave wid covers cols wid*64..wid*64+63
    int wid = t >> 6, l = t & 63;
    int g = l >> 4, c16 = l & 15;
    const short8* xb = (const short8*)(xbs + c16 * KPAD + g * 8);
    short8 af0 = xb[0], af1 = xb[4], af2 = xb[8];   // k = g*8 + {0,32,64}
    const short8* wp = (const short8*)W1p;
    #pragma unroll
    for (int ct = 0; ct < 4; ++ct) {
        int col = (wid * 4 + ct) * 16 + c16;
        f32x4 acc = {0.f, 0.f, 0.f, 0.f};
        acc = __builtin_amdgcn_mfma_f32_16x16x32_bf16(af0, wp[(0 * 4 + g) * D1 + col], acc, 0, 0, 0);
        acc = __builtin_amdgcn_mfma_f32_16x16x32_bf16(af1, wp[(1 * 4 + g) * D1 + col], acc, 0, 0, 0);
        acc = __builtin_amdgcn_mfma_f32_16x16x32_bf16(af2, wp[(2 * 4 + g) * D1 + col], acc, 0, 0, 0);
        #pragma unroll
        for (int r = 0; r < 4; ++r)
            hs[(g * 4 + r) * HS_LD + col] = acc[r];
    }
    __syncthreads();
    // pack fp8: thread t -> row t>>4, quad q=t&15; 4 iters of 16B-read/4B-store
    {
        int r = t >> 4, q = t & 15;
        #pragma unroll
        for (int j = 0; j < 4; ++j) {
            const float* src = hs + r * HS_LD + q * 4 + j * 64;
            int lo = __builtin_amdgcn_cvt_pk_fp8_f32(src[0], src[1], 0, false);
            int pk = __builtin_amdgcn_cvt_pk_fp8_f32(src[2], src[3], lo, true);
            *(int*)(h1f8 + (size_t)(n0 + r) * D1 + q * 4 + j * 64) = pk;
        }
    }
}

// ---------------- aggregation conv1 (wave/node, fp8 gather, 4x edge unroll) ----------------
__global__ __launch_bounds__(256) void k_aggr1(
        const int* __restrict__ row_off, const int* __restrict__ deg,
        const int2* __restrict__ adj,
        const unsigned char* __restrict__ h1f8,
        const float* __restrict__ al_s, const float* __restrict__ al_d,
        const float* __restrict__ wedot,
        const float* __restrict__ bnA1, const float* __restrict__ bnB1,
        unsigned short* __restrict__ h1p) {
    int wid = threadIdx.x >> 6, l = threadIdx.x & 63;
    int n = blockIdx.x * 4 + wid;
    if (n >= N_NODES) return;
    int h = l >> 3;
    float wd = wedot[h];
    float dn = al_d[n * HEADS + h];
    int r0 = row_off[n], cnt = deg[n];
    float a0 = 0.f, a1 = 0.f, a2 = 0.f, a3 = 0.f, den = 0.f, ea_sum = 0.f;
    for (int base = 0; base < cnt; base += 64) {
        int m = cnt - base; if (m > 64) m = 64;
        int sl = 0; float el = 0.f;
        if (l < m) {
            int2 se = adj[r0 + base + l];
            sl = se.x;
            el = __int_as_float(se.y);
        }
        int i = 0;
        for (; i + 3 < m; i += 4) {
            // issue 4 edges' loads before any accumulate (MLP x4)
            int s0 = __shfl(sl, i, 64);
            int s1 = __shfl(sl, i + 1, 64);
            int s2 = __shfl(sl, i + 2, 64);
            int s3 = __shfl(sl, i + 3, 64);
            float e0 = __shfl(el, i, 64);
            float e1 = __shfl(el, i + 1, 64);
            float e2 = __shfl(el, i + 2, 64);
            float e3 = __shfl(el, i + 3, 64);
            float as0 = al_s[s0 * HEADS + h];
            float as1 = al_s[s1 * HEADS + h];
            float as2 = al_s[s2 * HEADS + h];
            float as3 = al_s[s3 * HEADS + h];
            unsigned w80 = *(const unsigned*)(h1f8 + (size_t)s0 * D1 + l * 4);
            unsigned w81 = *(const unsigned*)(h1f8 + (size_t)s1 * D1 + l * 4);
            unsigned w82 = *(const unsigned*)(h1f8 + (size_t)s2 * D1 + l * 4);
            unsigned w83 = *(const unsigned*)(h1f8 + (size_t)s3 * D1 + l * 4);
            float aa0 = as0 + dn + e0 * wd; aa0 = aa0 > 0.f ? aa0 : 0.2f * aa0;
            float aa1 = as1 + dn + e1 * wd; aa1 = aa1 > 0.f ? aa1 : 0.2f * aa1;
            float aa2 = as2 + dn + e2 * wd; aa2 = aa2 > 0.f ? aa2 : 0.2f * aa2;
            float aa3 = as3 + dn + e3 * wd; aa3 = aa3 > 0.f ? aa3 : 0.2f * aa3;
            float w0 = __expf(aa0);
            float w1 = __expf(aa1);
            float w2 = __expf(aa2);
            float w3 = __expf(aa3);
            den += (w0 + w1) + (w2 + w3);
            ea_sum += (e0 + e1) + (e2 + e3);
            f32x2 lo0 = __builtin_amdgcn_cvt_pk_f32_fp8(w80, false);
            f32x2 hi0 = __builtin_amdgcn_cvt_pk_f32_fp8(w80, true);
            f32x2 lo1 = __builtin_amdgcn_cvt_pk_f32_fp8(w81, false);
            f32x2 hi1 = __builtin_amdgcn_cvt_pk_f32_fp8(w81, true);
            f32x2 lo2 = __builtin_amdgcn_cvt_pk_f32_fp8(w82, false);
            f32x2 hi2 = __builtin_amdgcn_cvt_pk_f32_fp8(w82, true);
            f32x2 lo3 = __builtin_amdgcn_cvt_pk_f32_fp8(w83, false);
            f32x2 hi3 = __builtin_amdgcn_cvt_pk_f32_fp8(w83, true);
            a0 += (w0 * lo0.x + w1 * lo1.x) + (w2 * lo2.x + w3 * lo3.x);
            a1 += (w0 * lo0.y + w1 * lo1.y) + (w2 * lo2.y + w3 * lo3.y);
            a2 += (w0 * hi0.x + w1 * hi1.x) + (w2 * hi2.x + w3 * hi3.x);
            a3 += (w0 * hi0.y + w1 * hi1.y) + (w2 * hi2.y + w3 * hi3.y);
        }
        for (; i < m; ++i) {   // tail (<=3)
            int s = __shfl(sl, i, 64);
            float eav = __shfl(el, i, 64);
            float a = al_s[s * HEADS + h] + dn + eav * wd;
            a = a > 0.f ? a : 0.2f * a;
            float w = __expf(a);
            den += w;
            ea_sum += eav;
            unsigned w8 = *(const unsigned*)(h1f8 + (size_t)s * D1 + l * 4);
            f32x2 lo = __builtin_amdgcn_cvt_pk_f32_fp8(w8, false);
            f32x2 hi = __builtin_amdgcn_cvt_pk_f32_fp8(w8, true);
            a0 += w * lo.x; a1 += w * lo.y;
            a2 += w * hi.x; a3 += w * hi.y;
        }
    }
    {   // self loop, attr = mean of incoming (0 if none)
        float la = ea_sum / (float)(cnt > 0 ? cnt : 1);
        float a = al_s[n * HEADS + h] + dn + la * wd;
        a = a > 0.f ? a : 0.2f * a;
        float w = __expf(a);
        den += w;
        unsigned w8 = *(const unsigned*)(h1f8 + (size_t)n * D1 + l * 4);
        f32x2 lo = __builtin_amdgcn_cvt_pk_f32_fp8(w8, false);
        f32x2 hi = __builtin_amdgcn_cvt_pk_f32_fp8(w8, true);
        a0 += w * lo.x; a1 += w * lo.y;
        a2 += w * hi.x; a3 += w * hi.y;
    }
    float inv = 1.f / den;
    int c = l * 4;
    float4 A = *(const float4*)(bnA1 + c);
    float4 B = *(const float4*)(bnB1 + c);
    ushort4 o;
    o.x = f2bf(fmaxf(a0 * inv * A.x + B.x, 0.f));
    o.y = f2bf(fmaxf(a1 * inv * A.y + B.y, 0.f));
    o.z = f2bf(fmaxf(a2 * inv * A.z + B.z, 0.f));
    o.w = f2bf(fmaxf(a3 * inv * A.w + B.w, 0.f));
    *(ushort4*)(h1p + (size_t)n * D1 + c) = o;
}

// ---------------- conv2 ----------------

// h1p(bf16) @ W2p(bf16) -> h2f8 (fp8 e4m3) via MFMA, fused alpha2 (f32-exact).
__global__ __launch_bounds__(256) void k_gemm2(const unsigned short* __restrict__ h1p,
                                               const unsigned short* __restrict__ W2p,
                                               const float* __restrict__ as2,
                                               const float* __restrict__ ad2,
                                               unsigned char* __restrict__ h2f8,
                                               float* __restrict__ al_s2,
                                               float* __restrict__ al_d2) {
    int wid = threadIdx.x >> 6, l = threadIdx.x & 63;
    int wave = blockIdx.x * 4 + wid;
    if (wave >= N_NODES / 16) return;
    int n0 = wave * 16;
    int g = l >> 4;        // k-subgroup 0..3
    int c16 = l & 15;      // col within 16 / A-row within 16
    f32x4 acc0 = {0.f, 0.f, 0.f, 0.f};
    f32x4 acc1 = {0.f, 0.f, 0.f, 0.f};
    const short8* ap = (const short8*)(h1p + (size_t)(n0 + c16) * D1 + g * 8);
    const short8* wp = (const short8*)W2p;
    #pragma unroll
    for (int ks = 0; ks < 8; ++ks) {
        short8 afrag = ap[ks * 4];                     // +ks*32 bf16
        short8 b0 = wp[(ks * 4 + g) * 32 + c16];
        short8 b1 = wp[(ks * 4 + g) * 32 + 16 + c16];
        acc0 = __builtin_amdgcn_mfma_f32_16x16x32_bf16(afrag, b0, acc0, 0, 0, 0);
        acc1 = __builtin_amdgcn_mfma_f32_16x16x32_bf16(afrag, b1, acc1, 0, 0, 0);
    }
    // C layout: col = lane&15, row = (lane>>4)*4 + reg
    float s0 = as2[c16], s1 = as2[16 + c16];
    float d0 = ad2[c16], d1 = ad2[16 + c16];
    float ps[4], pd[4];
    #pragma unroll
    for (int r = 0; r < 4; ++r) {
        int node = n0 + g * 4 + r;
        int p0 = __builtin_amdgcn_cvt_pk_fp8_f32(acc0[r], acc0[r], 0, false);
        int p1 = __builtin_amdgcn_cvt_pk_fp8_f32(acc1[r], acc1[r], 0, false);
        h2f8[(size_t)node * HID + c16]      = (unsigned char)p0;
        h2f8[(size_t)node * HID + 16 + c16] = (unsigned char)p1;
        ps[r] = acc0[r] * s0 + acc1[r] * s1;
        pd[r] = acc0[r] * d0 + acc1[r] * d1;
    }
    #pragma unroll
    for (int off = 1; off < 16; off <<= 1) {
        #pragma unroll
        for (int r = 0; r < 4; ++r) {
            ps[r] += __shfl_xor(ps[r], off, 64);
            pd[r] += __shfl_xor(pd[r], off, 64);
        }
    }
    if (c16 == 0) {
        #pragma unroll
        for (int r = 0; r < 4; ++r) {
            int node = n0 + g * 4 + r;
            al_s2[node] = ps[r];
            al_d2[node] = pd[r];
        }
    }
}

// aggregation conv2: oct-split — 8-lane group per edge, 8 edges/iter,
// lane owns 4 channels (uint fp8 gather). Cross-group reduce at end.
__global__ __launch_bounds__(256) void k_aggr2(
        const int* __restrict__ row_off, const int* __restrict__ deg,
        const int2* __restrict__ adj,
        const unsigned char* __restrict__ h2f8,
        const float* __restrict__ al_s2, const float* __restrict__ al_d2,
        const float* __restrict__ wedot,
        const float* __restrict__ bnA2, const float* __restrict__ bnB2,
        float* __restrict__ h2p) {
    int wid = threadIdx.x >> 6, l = threadIdx.x & 63;
    int n = blockIdx.x * 4 + wid;
    if (n >= N_NODES) return;
    int g = l >> 3, c8 = l & 7;           // edge-group, channel-quad index
    float wd = wedot[HEADS];
    float dn = al_d2[n];
    int r0 = row_off[n], cnt = deg[n];
    float a0 = 0.f, a1 = 0.f, a2 = 0.f, a3 = 0.f, den = 0.f, ea_sum = 0.f;
    for (int base = 0; base < cnt; base += 64) {
        int m = cnt - base; if (m > 64) m = 64;
        int sl = 0; float el = 0.f;
        if (l < m) {
            int2 se = adj[r0 + base + l];
            sl = se.x;
            el = __int_as_float(se.y);
        }
        for (int i = 0; i < m; i += 8) {
            int j = i + g;
            int jj = j < m ? j : 0;
            int s = __shfl(sl, jj, 64);
            float eav = __shfl(el, jj, 64);
            if (j < m) {
                float a = al_s2[s] + dn + eav * wd;
                a = a > 0.f ? a : 0.2f * a;
                float w = __expf(a);
                den += w;
                ea_sum += eav;
                unsigned w8 = *(const unsigned*)(h2f8 + (size_t)s * HID + c8 * 4);
                f32x2 lo = __builtin_amdgcn_cvt_pk_f32_fp8(w8, false);
                f32x2 hi = __builtin_amdgcn_cvt_pk_f32_fp8(w8, true);
                a0 += w * lo.x; a1 += w * lo.y;
                a2 += w * hi.x; a3 += w * hi.y;
            }
        }
    }
    // reduce across the 8 edge-groups (c8 stays aligned under xor of bits 3..5)
    #pragma unroll
    for (int off = 8; off < 64; off <<= 1) {
        a0 += __shfl_xor(a0, off, 64);
        a1 += __shfl_xor(a1, off, 64);
        a2 += __shfl_xor(a2, off, 64);
        a3 += __shfl_xor(a3, off, 64);
        den += __shfl_xor(den, off, 64);
        ea_sum += __shfl_xor(ea_sum, off, 64);
    }
    {   // self loop (all lanes add identically post-reduce)
        float la = ea_sum / (float)(cnt > 0 ? cnt : 1);
        float a = al_s2[n] + dn + la * wd;
        a = a > 0.f ? a : 0.2f * a;
        float w = __expf(a);
        den += w;
        unsigned w8 = *(const unsigned*)(h2f8 + (size_t)n * HID + c8 * 4);
        f32x2 lo = __builtin_amdgcn_cvt_pk_f32_fp8(w8, false);
        f32x2 hi = __builtin_amdgcn_cvt_pk_f32_fp8(w8, true);
        a0 += w * lo.x; a1 += w * lo.y;
        a2 += w * hi.x; a3 += w * hi.y;
    }
    if (g == 0) {
        float inv = 1.f / den;
        int c = c8 * 4;
        float4 A = *(const float4*)(bnA2 + c);
        float4 B = *(const float4*)(bnB2 + c);
        float4 y;
        y.x = fmaxf(a0 * inv * A.x + B.x, 0.f);
        y.y = fmaxf(a1 * inv * A.y + B.y, 0.f);
        y.z = fmaxf(a2 * inv * A.z + B.z, 0.f);
        y.w = fmaxf(a3 * inv * A.w + B.w, 0.f);
        *(float4*)(h2p + (size_t)n * HID + c) = y;
    }
}

// pool (mean over sorted batch segments) + fc, one block per graph
__global__ __launch_bounds__(64) void k_poolfc(const float* __restrict__ h2p,
                                               const int* __restrict__ batch,
                                               const float* __restrict__ fcW,
                                               const float* __restrict__ fcb,
                                               float* __restrict__ out) {
    int g = blockIdx.x;
    int l = threadIdx.x;
    auto lb = [&](int key) {
        int lo = 0, hi = N_NODES;
        while (lo < hi) {
            int mid = (lo + hi) >> 1;
            if (batch[mid] < key) lo = mid + 1; else hi = mid;
        }
        return lo;
    };
    int s0 = lb(g), s1 = lb(g + 1);
    int c = l & 31, half = l >> 5;
    float acc = 0.f;
    for (int r = s0 + half; r < s1; r += 2)
        acc += h2p[(size_t)r * HID + c];
    acc += __shfl_xor(acc, 32, 64);
    int cn = s1 - s0;
    float mean = acc / (float)(cn > 0 ? cn : 1);
    float p = mean * fcW[c];
    #pragma unroll
    for (int off = 1; off < 32; off <<= 1) p += __shfl_xor(p, off, 64);
    if (l == 0) out[g] = p + fcb[0];
}

// ---------------- launch ----------------

extern "C" void kernel_launch(void* const* d_in, const int* in_sizes, int n_in,
                              void* d_out, int out_size, void* d_ws, size_t ws_size,
                              hipStream_t stream) {
    const float* x    = (const float*)d_in[0];
    const int*   ei   = (const int*)  d_in[1];
    const float* ea   = (const float*)d_in[2];
    const int*   batch= (const int*)  d_in[3];
    const float* W1   = (const float*)d_in[4];
    const float* We1  = (const float*)d_in[5];
    const float* as1  = (const float*)d_in[6];
    const float* ad1  = (const float*)d_in[7];
    const float* ae1  = (const float*)d_in[8];
    const float* b1   = (const float*)d_in[9];
    const float* g1   = (const float*)d_in[10];
    const float* be1  = (const float*)d_in[11];
    const float* m1   = (const float*)d_in[12];
    const float* v1   = (const float*)d_in[13];
    const float* W2   = (const float*)d_in[14];
    const float* We2  = (const float*)d_in[15];
    const float* as2  = (const float*)d_in[16];
    const float* ad2  = (const float*)d_in[17];
    const float* ae2  = (const float*)d_in[18];
    const float* b2   = (const float*)d_in[19];
    const float* g2   = (const float*)d_in[20];
    const float* be2  = (const float*)d_in[21];
    const float* m2   = (const float*)d_in[22];
    const float* v2   = (const float*)d_in[23];
    const float* fcW  = (const float*)d_in[24];
    const float* fcb  = (const float*)d_in[25];
    float* out = (float*)d_out;

    char* ws = (char*)d_ws;
    size_t off = 0;
    auto alloc = [&](size_t bytes) -> void* {
        void* p = ws + off;
        off += (bytes + 255) & ~(size_t)255;
        return p;
    };
    int*   deg     = (int*)  alloc((size_t)N_NODES * 4);
    int*   row_off = (int*)  alloc((size_t)N_NODES * 4);
    int*   cursor  = (int*)  alloc((size_t)N_NODES * 4);
    int2*  adj     = (int2*) alloc((size_t)N_EDGES * 8);
    float* al_s1   = (float*)alloc((size_t)N_NODES * HEADS * 4);
    float* al_d1   = (float*)alloc((size_t)N_NODES * HEADS * 4);
    float* al_s2   = (float*)alloc((size_t)N_NODES * 4);
    float* al_d2   = (float*)alloc((size_t)N_NODES * 4);
    float* wedot   = (float*)alloc(16 * 4);
    float* va      = (float*)alloc((size_t)2 * HEADS * F_IN * 4);
    int*   partials= (int*)  alloc(64 * 4);
    float* bnA1    = (float*)alloc((size_t)D1 * 4);
    float* bnB1    = (float*)alloc((size_t)D1 * 4);
    float* bnA2    = (float*)alloc((size_t)HID * 4);
    float* bnB2    = (float*)alloc((size_t)HID * 4);
    unsigned short* W1p = (unsigned short*)alloc((size_t)KPAD * D1 * 2);
    unsigned short* W2p = (unsigned short*)alloc((size_t)D1 * HID * 2);
    unsigned char*  h1f8 = (unsigned char*)alloc((size_t)N_NODES * D1);
    unsigned short* h1p = (unsigned short*)alloc((size_t)N_NODES * D1 * 2);
    unsigned char*  h2f8 = (unsigned char*)alloc((size_t)N_NODES * HID);
    float* h2p     = (float*)alloc((size_t)N_NODES * HID * 4);
    (void)ws_size; (void)in_sizes; (void)n_in; (void)out_size;

    hipMemsetAsync(deg, 0, (size_t)N_NODES * 4, stream);

    k_deg_setup<<<DEGBLK + 136, 256, 0, stream>>>(ei, deg, W1, W2, We1, ae1, We2, ae2,
                                                  as1, ad1, b1, g1, be1, m1, v1,
                                                  b2, g2, be2, m2, v2,
                                                  W1p, W2p, va, wedot,
                                                  bnA1, bnB1, bnA2, bnB2);
    k_partial<<<NCHUNK, 256, 0, stream>>>(deg, partials);
    k_scanc<<<NCHUNK, 256, 0, stream>>>(deg, partials, row_off, cursor);
    k_fill<<<(N_EDGES + 255) / 256, 256, 0, stream>>>(ei, ea, cursor, adj);

    k_conv1<<<N_NODES / 16, 256, 0, stream>>>(x, W1p, va, h1f8, al_s1, al_d1);
    k_aggr1<<<(N_NODES + 3) / 4, 256, 0, stream>>>(row_off, deg, adj,
                                                   h1f8, al_s1, al_d1, wedot,
                                                   bnA1, bnB1, h1p);

    k_gemm2<<<(N_NODES / 16 + 3) / 4, 256, 0, stream>>>(h1p, W2p, as2, ad2, h2f8, al_s2, al_d2);
    k_aggr2<<<(N_NODES + 3) / 4, 256, 0, stream>>>(row_off, deg, adj,
                                                   h2f8, al_s2, al_d2, wedot, bnA2, bnB2, h2p);
    k_poolfc<<<G_GRAPHS, 64, 0, stream>>>(h2p, batch, fcW, fcb, out);
}